// Round 2
// 1959.076 us; speedup vs baseline: 1.6450x; 1.6450x over previous
//
#include <hip/hip_runtime.h>
#include <hip/hip_bf16.h>
#include <stdint.h>

#define B_ 32
#define S_ 128
#define SM1 127
#define E_ 300
#define H_ 1024
#define V_ 32000
#define M_ 4064   // B_*SM1

typedef __bf16 bf16x8 __attribute__((ext_vector_type(8)));
typedef float f32x4 __attribute__((ext_vector_type(4)));

// workspace layout (bytes)
#define WS_CTR   0            // 127 x u32 barrier counters (zeroed)
#define WS_NLL   1024         // f32 nll accumulator (zeroed)
#define WS_HFRAG 4096         // 2 x 65536 h double-buffer in A-frag order (zeroed)
#define WS_PRE   135168       // 127*32*1024 f32 = x@Wxh + bh
#define WS_HS    16781312     // 4064*1024 bf16, row m = b*127+s
#define WS_WBT   25104384     // 32000*1024 bf16, Wout transposed
// end = 90,640,384 bytes

// Coherent (cross-XCD) 16B access: sc0 sc1 bypasses non-coherent L1/L2 and
// reads/writes at the Infinity-Cache coherence point. This replaces the
// whole-L2 wbl2/inv traffic that __threadfence()/ACQUIRE-poll generated.
union frag_cvt { f32x4 f; bf16x8 h; };

__device__ __forceinline__ f32x4 coh_load16(const uint8_t* p) {
  f32x4 r;
  asm volatile("global_load_dwordx4 %0, %1, off sc0 sc1"
               : "=v"(r) : "v"(p) : "memory");
  return r;
}
__device__ __forceinline__ void coh_store16(uint8_t* p, f32x4 v) {
  asm volatile("global_store_dwordx4 %0, %1, off sc0 sc1"
               :: "v"(p), "v"(v) : "memory");
}

// ---------------- K0: Wout (H,V) f32 -> (V,H) bf16 transpose ----------------
__global__ __launch_bounds__(256) void k_wout_cvt(const float* __restrict__ Wout,
                                                  __hip_bfloat16* __restrict__ bt) {
  __shared__ float t[32][33];
  int vt = blockIdx.x / 32, kt = blockIdx.x - vt * 32;
  int tx = threadIdx.x & 31, ty = threadIdx.x >> 5;
#pragma unroll
  for (int i = 0; i < 4; i++) {
    int k = kt * 32 + ty + i * 8;
    t[ty + i * 8][tx] = Wout[(size_t)k * V_ + vt * 32 + tx];
  }
  __syncthreads();
#pragma unroll
  for (int i = 0; i < 4; i++) {
    int v = vt * 32 + ty + i * 8;
    bt[(size_t)v * H_ + kt * 32 + tx] = __float2bfloat16(t[tx][ty + i * 8]);
  }
}

// ---------------- K1: pre[s*32+b][j] = wordvec[sent[b][s]] @ Wxh + bh ----------------
__global__ __launch_bounds__(256) void k_pre(const int* __restrict__ sent,
    const float* __restrict__ wordvec, const float* __restrict__ Wxh,
    const float* __restrict__ bh, float* __restrict__ pre) {
  __shared__ float e[8 * E_];
  int r0 = blockIdx.x * 8;           // rows r = s*32+b, 8 consecutive share s
  int s = r0 >> 5, b0 = r0 & 31;
  for (int idx = threadIdx.x; idx < 8 * E_; idx += 256) {
    int i = idx / E_, k = idx - i * E_;
    int tok = sent[(b0 + i) * S_ + s];
    e[idx] = wordvec[(size_t)tok * E_ + k];
  }
  __syncthreads();
  int j0 = threadIdx.x * 4;
  float4 acc[8];
#pragma unroll
  for (int i = 0; i < 8; i++) acc[i] = make_float4(0.f, 0.f, 0.f, 0.f);
  for (int k = 0; k < E_; k++) {
    float4 w = *(const float4*)&Wxh[k * H_ + j0];
#pragma unroll
    for (int i = 0; i < 8; i++) {
      float ev = e[i * E_ + k];
      acc[i].x += ev * w.x; acc[i].y += ev * w.y;
      acc[i].z += ev * w.z; acc[i].w += ev * w.w;
    }
  }
  float4 bias = *(const float4*)&bh[j0];
#pragma unroll
  for (int i = 0; i < 8; i++) {
    float4 o = make_float4(acc[i].x + bias.x, acc[i].y + bias.y,
                           acc[i].z + bias.z, acc[i].w + bias.w);
    *(float4*)&pre[(size_t)(r0 + i) * H_ + j0] = o;
  }
}

// ---------------- K2: persistent recurrence, 64 blocks, barrier per step ----------------
// Block jb owns h-columns [jb*16, jb*16+16). Whh slice LDS-stationary in exact
// MFMA B-frag order; h passed between steps via global double-buffer in exact
// MFMA A-frag order (region (kc,t): lane l holds h[t*16+(l&15)][kc*32+(l>>4)*8+i]).
// Cross-block h exchange uses sc0|sc1 point-coherent loads/stores + relaxed
// agent atomics: NO per-step L2 writeback/invalidate (was ~7 us/step of the
// previous version's 14 us/step).
__global__ __launch_bounds__(256) void k_rnn(const float* __restrict__ Whh,
    const float* __restrict__ pre, __hip_bfloat16* __restrict__ hs,
    uint8_t* __restrict__ ws) {
  __shared__ __hip_bfloat16 ldsB[32 * 64 * 8];   // 32 KB, B-frag order
  __shared__ float ldsP[4 * 8 * 64];             // 8 KB cross-wave partials
  __shared__ __hip_bfloat16 ldsCt[32 * 24];      // C->A-frag transpose, padded
  const int jb = blockIdx.x;                     // 0..63
  const int tid = threadIdx.x;
  const int lane = tid & 63, w = tid >> 6;
  uint32_t* ctr = (uint32_t*)(ws + WS_CTR);
  uint8_t* hfrag = ws + WS_HFRAG;

  // stage Whh[:, jb*16 .. +16) as bf16 B-fragments
  for (int idx = tid; idx < 32 * 64; idx += 256) {
    int kc = idx >> 6, l = idx & 63;
    int n = l & 15;
    int k0 = kc * 32 + ((l >> 4) << 3);
    bf16x8 v;
#pragma unroll
    for (int i = 0; i < 8; i++)
      v[i] = (__bf16)Whh[(size_t)(k0 + i) * H_ + jb * 16 + n];
    *(bf16x8*)&ldsB[idx * 8] = v;
  }
  __syncthreads();

  for (int s = 0; s < SM1; s++) {
    const uint8_t* rbuf = hfrag + ((s & 1) ? 65536 : 0);
    uint8_t* wbuf = hfrag + ((s & 1) ? 0 : 65536);
    f32x4 acc0 = {0.f, 0.f, 0.f, 0.f}, acc1 = {0.f, 0.f, 0.f, 0.f};
    const int kc0 = w * 8;

    // batch-issue all 16 coherent A-frag loads, single drain, then MFMA
    bf16x8 a0[8], a1[8];
#pragma unroll
    for (int i = 0; i < 8; i++) {
      int kc = kc0 + i;
      frag_cvt c0, c1;
      c0.f = coh_load16(rbuf + (((kc * 2 + 0) * 64 + lane) << 4));
      c1.f = coh_load16(rbuf + (((kc * 2 + 1) * 64 + lane) << 4));
      a0[i] = c0.h; a1[i] = c1.h;
    }
    asm volatile("s_waitcnt vmcnt(0)" ::: "memory");
    __builtin_amdgcn_sched_barrier(0);   // rule #18: keep MFMAs below the drain
#pragma unroll
    for (int i = 0; i < 8; i++) {
      int kc = kc0 + i;
      bf16x8 b0 = *(const bf16x8*)&ldsB[(kc * 64 + lane) * 8];
      acc0 = __builtin_amdgcn_mfma_f32_16x16x32_bf16(a0[i], b0, acc0, 0, 0, 0);
      acc1 = __builtin_amdgcn_mfma_f32_16x16x32_bf16(a1[i], b0, acc1, 0, 0, 0);
    }
#pragma unroll
    for (int r = 0; r < 4; r++) {
      ldsP[(w * 8 + r) * 64 + lane] = acc0[r];
      ldsP[(w * 8 + 4 + r) * 64 + lane] = acc1[r];
    }
    __syncthreads();
    // epilogue split: wave w -> m-tile t=w>>1, regs (w&1)*2 + {0,1}
    {
      int t = w >> 1;
      int jl = lane & 15;
#pragma unroll
      for (int rr = 0; rr < 2; rr++) {
        int r = ((w & 1) << 1) + rr;
        float sum = 0.f;
#pragma unroll
        for (int p = 0; p < 4; p++) sum += ldsP[(p * 8 + t * 4 + r) * 64 + lane];
        int b = t * 16 + ((lane >> 4) << 2) + r;           // C/D row mapping (m89)
        float x = sum + pre[(size_t)(s * 32 + b) * H_ + jb * 16 + jl];
        float h = tanhf(x);
        __hip_bfloat16 hb = __float2bfloat16(h);
        hs[(size_t)(b * SM1 + s) * H_ + jb * 16 + jl] = hb;
        ldsCt[b * 24 + jl] = hb;
      }
    }
    __syncthreads();
    // wave 0: transpose to A-frag order, coherent-store next-step h buffer
    // (this block's 16 columns = half of regions (jb>>1)*2 + {0,1})
    if (w == 0 && (lane >> 5) == (jb & 1)) {
      int kcw = jb >> 1;
#pragma unroll
      for (int t2 = 0; t2 < 2; t2++) {
        frag_cvt c;
        c.h = *(const bf16x8*)&ldsCt[(t2 * 16 + (lane & 15)) * 24 +
                                     (((lane >> 4) & 1) << 3)];
        coh_store16(wbuf + (((kcw * 2 + t2) * 64 + lane) << 4), c.f);
      }
    }
    // relaxed barrier: stores already point-coherent; no wbl2/inv needed.
    // Release invariant: tid0 shares wave 0's vmcnt with the h stores, so
    // vmcnt(0) => stores globally visible before the increment. All waves'
    // step-s rbuf reads retired at the first __syncthreads of step s.
    if (s < SM1 - 1) {
      if (tid == 0) {
        asm volatile("s_waitcnt vmcnt(0)" ::: "memory");
        __hip_atomic_fetch_add(&ctr[s], 1u, __ATOMIC_RELAXED, __HIP_MEMORY_SCOPE_AGENT);
        while (__hip_atomic_load(&ctr[s], __ATOMIC_RELAXED, __HIP_MEMORY_SCOPE_AGENT) < 64u)
          __builtin_amdgcn_s_sleep(2);
      }
      __syncthreads();
    }
  }
}

// ---------------- K3: logits = hs(4064x1024) @ Wout + bout, bf16 MFMA ----------------
__global__ __launch_bounds__(256) void k_gemm(const __hip_bfloat16* __restrict__ A,
    const __hip_bfloat16* __restrict__ Bt, const float* __restrict__ bout,
    float* __restrict__ C) {
  __shared__ __hip_bfloat16 lA[128 * 64];
  __shared__ __hip_bfloat16 lB[128 * 64];
  int bid = blockIdx.x;
  int idx = bid & 255;
  int mt = idx & 31;
  int nt = ((bid >> 8) << 3) + (idx >> 5);   // N-panel swizzle: 32 mt share 8 nt panels
  int tid = threadIdx.x;
  int lane = tid & 63, w = tid >> 6;
  int wm = (w >> 1) << 6, wn = (w & 1) << 6;
  int mbase = mt * 128, nbase = nt * 128;
  f32x4 acc[4][4];
#pragma unroll
  for (int t = 0; t < 4; t++)
#pragma unroll
    for (int u = 0; u < 4; u++) acc[t][u] = (f32x4){0.f, 0.f, 0.f, 0.f};

  for (int k0 = 0; k0 < H_; k0 += 64) {
#pragma unroll
    for (int r = 0; r < 4; r++) {
      int L = r * 4096 + tid * 16;
      int row = L >> 7;
      int gphys = (L >> 4) & 7;
      int glog = gphys ^ (row & 7);          // XOR swizzle kills frag-read conflicts
      int m = mbase + row; if (m > M_ - 1) m = M_ - 1;
      const uint8_t* g = (const uint8_t*)A + ((size_t)m * H_ + k0) * 2 + glog * 16;
      __builtin_amdgcn_global_load_lds((const __attribute__((address_space(1))) uint32_t*)g,
          (__attribute__((address_space(3))) uint32_t*)((uint8_t*)lA + L), 16, 0, 0);
    }
#pragma unroll
    for (int r = 0; r < 4; r++) {
      int L = r * 4096 + tid * 16;
      int row = L >> 7;
      int gphys = (L >> 4) & 7;
      int glog = gphys ^ (row & 7);
      int n = nbase + row;
      const uint8_t* g = (const uint8_t*)Bt + ((size_t)n * H_ + k0) * 2 + glog * 16;
      __builtin_amdgcn_global_load_lds((const __attribute__((address_space(1))) uint32_t*)g,
          (__attribute__((address_space(3))) uint32_t*)((uint8_t*)lB + L), 16, 0, 0);
    }
    __builtin_amdgcn_s_waitcnt(0);
    __syncthreads();
#pragma unroll
    for (int kk = 0; kk < 64; kk += 32) {
      bf16x8 af[4], bfr[4];
      int quad = lane >> 4;
#pragma unroll
      for (int t = 0; t < 4; t++) {
        int row = wm + t * 16 + (lane & 15);
        int gphys = ((kk >> 3) + quad) ^ (row & 7);
        af[t] = *(const bf16x8*)&lA[row * 64 + gphys * 8];
      }
#pragma unroll
      for (int u = 0; u < 4; u++) {
        int row = wn + u * 16 + (lane & 15);
        int gphys = ((kk >> 3) + quad) ^ (row & 7);
        bfr[u] = *(const bf16x8*)&lB[row * 64 + gphys * 8];
      }
#pragma unroll
      for (int t = 0; t < 4; t++)
#pragma unroll
        for (int u = 0; u < 4; u++)
          acc[t][u] = __builtin_amdgcn_mfma_f32_16x16x32_bf16(af[t], bfr[u], acc[t][u], 0, 0, 0);
    }
    __syncthreads();
  }
  int quad = lane >> 4, l15 = lane & 15;
#pragma unroll
  for (int u = 0; u < 4; u++) {
    int col = nbase + wn + u * 16 + l15;
    float bias = bout[col];
#pragma unroll
    for (int t = 0; t < 4; t++) {
      int rowb = mbase + wm + t * 16 + quad * 4;
#pragma unroll
      for (int r = 0; r < 4; r++) {
        int row = rowb + r;
        if (row < M_) C[(size_t)row * V_ + col] = acc[t][u][r] + bias;
      }
    }
  }
}

// ---------------- K4: masked NLL via online logsumexp ----------------
__global__ __launch_bounds__(256) void k_loss(const float* __restrict__ logits,
    const int* __restrict__ sent, const int* __restrict__ length,
    float* __restrict__ nll_acc) {
  int r = blockIdx.x;
  int b = r / SM1, s = r - b * SM1;
  if (s >= length[b]) return;
  const float* row = logits + (size_t)r * V_;
  float m = -3.0e38f, l = 0.f;
  for (int v = threadIdx.x; v < V_; v += 256) {
    float x = row[v];
    float nm = fmaxf(m, x);
    l = l * __expf(m - nm) + __expf(x - nm);
    m = nm;
  }
#pragma unroll
  for (int off = 1; off < 64; off <<= 1) {
    float m2 = __shfl_xor(m, off);
    float l2 = __shfl_xor(l, off);
    float nm = fmaxf(m, m2);
    l = l * __expf(m - nm) + l2 * __expf(m2 - nm);
    m = nm;
  }
  __shared__ float sm[4], sl[4];
  int wv = threadIdx.x >> 6;
  if ((threadIdx.x & 63) == 0) { sm[wv] = m; sl[wv] = l; }
  __syncthreads();
  if (threadIdx.x == 0) {
    m = sm[0]; l = sl[0];
    for (int p = 1; p < 4; p++) {
      float nm = fmaxf(m, sm[p]);
      l = l * __expf(m - nm) + sl[p] * __expf(sm[p] - nm);
      m = nm;
    }
    int tgt = sent[b * S_ + s + 1];
    float nll = m + logf(l) - row[tgt];
    atomicAdd(nll_acc, nll);
  }
}

// ---------------- K5: loss = nll_sum / sum(length) ----------------
__global__ void k_final(const float* __restrict__ nll_acc,
                        const int* __restrict__ length, float* __restrict__ out) {
  float cnt = 0.f;
  for (int b = 0; b < B_; b++) cnt += (float)length[b];
  out[0] = nll_acc[0] / cnt;
}

extern "C" void kernel_launch(void* const* d_in, const int* in_sizes, int n_in,
                              void* d_out, int out_size, void* d_ws, size_t ws_size,
                              hipStream_t stream) {
  const int* sent      = (const int*)d_in[0];
  const int* length    = (const int*)d_in[1];
  const float* wordvec = (const float*)d_in[2];
  const float* Wxh     = (const float*)d_in[3];
  const float* Whh     = (const float*)d_in[4];
  const float* bh      = (const float*)d_in[5];
  const float* Wout    = (const float*)d_in[6];
  const float* bout    = (const float*)d_in[7];
  float* out = (float*)d_out;
  uint8_t* ws = (uint8_t*)d_ws;

  // zero barrier counters + nll accumulator + h0 frag buffers
  hipMemsetAsync(ws, 0, 135168, stream);

  __hip_bfloat16* wbt = (__hip_bfloat16*)(ws + WS_WBT);
  float* pre          = (float*)(ws + WS_PRE);
  __hip_bfloat16* hs  = (__hip_bfloat16*)(ws + WS_HS);
  float* logits       = out + 1;

  k_wout_cvt<<<32000, 256, 0, stream>>>(Wout, wbt);
  k_pre<<<508, 256, 0, stream>>>(sent, wordvec, Wxh, bh, pre);
  k_rnn<<<64, 256, 0, stream>>>(Whh, pre, hs, ws);
  k_gemm<<<8000, 256, 0, stream>>>(hs, wbt, bout, logits);
  k_loss<<<4064, 256, 0, stream>>>(logits, sent, length, (float*)(ws + WS_NLL));
  k_final<<<1, 1, 0, stream>>>((const float*)(ws + WS_NLL), length, out);
}

// Round 3
// 1715.010 us; speedup vs baseline: 1.8791x; 1.1423x over previous
//
#include <hip/hip_runtime.h>
#include <hip/hip_bf16.h>
#include <stdint.h>

#define B_ 32
#define S_ 128
#define SM1 127
#define E_ 300
#define H_ 1024
#define V_ 32000
#define M_ 4064   // B_*SM1

typedef __bf16 bf16x8 __attribute__((ext_vector_type(8)));
typedef float f32x4 __attribute__((ext_vector_type(4)));

// workspace layout (bytes)
#define WS_CTR   0            // 127 x u32 barrier counters (zeroed)
#define WS_NLL   1024         // f32 nll accumulator (zeroed)
#define WS_HFRAG 4096         // 2 x 65536 h double-buffer in A-frag order (zeroed)
#define WS_PRE   135168       // 127*32*1024 f32 = x@Wxh + bh
#define WS_HS    16781312     // 4064*1024 bf16, row m = b*127+s
#define WS_WBT   25104384     // 32000*1024 bf16, Wout transposed
// end = 90,640,384 bytes

// Coherent (cross-XCD) 16B access: sc0 sc1 bypasses non-coherent L1/L2 and
// reads/writes at the Infinity-Cache coherence point.
union frag_cvt { f32x4 f; bf16x8 h; };

__device__ __forceinline__ f32x4 coh_load16(const uint8_t* p) {
  f32x4 r;
  asm volatile("global_load_dwordx4 %0, %1, off sc0 sc1"
               : "=v"(r) : "v"(p) : "memory");
  return r;
}
__device__ __forceinline__ void coh_store16(uint8_t* p, f32x4 v) {
  asm volatile("global_store_dwordx4 %0, %1, off sc0 sc1"
               :: "v"(p), "v"(v) : "memory");
}

// ---------------- K0: Wout (H,V) f32 -> (V,H) bf16 transpose ----------------
__global__ __launch_bounds__(256) void k_wout_cvt(const float* __restrict__ Wout,
                                                  __hip_bfloat16* __restrict__ bt) {
  __shared__ float t[32][33];
  int vt = blockIdx.x / 32, kt = blockIdx.x - vt * 32;
  int tx = threadIdx.x & 31, ty = threadIdx.x >> 5;
#pragma unroll
  for (int i = 0; i < 4; i++) {
    int k = kt * 32 + ty + i * 8;
    t[ty + i * 8][tx] = Wout[(size_t)k * V_ + vt * 32 + tx];
  }
  __syncthreads();
#pragma unroll
  for (int i = 0; i < 4; i++) {
    int v = vt * 32 + ty + i * 8;
    bt[(size_t)v * H_ + kt * 32 + tx] = __float2bfloat16(t[tx][ty + i * 8]);
  }
}

// ---------------- K1: pre[s*32+b][j] = wordvec[sent[b][s]] @ Wxh + bh ----------------
__global__ __launch_bounds__(256) void k_pre(const int* __restrict__ sent,
    const float* __restrict__ wordvec, const float* __restrict__ Wxh,
    const float* __restrict__ bh, float* __restrict__ pre) {
  __shared__ float e[8 * E_];
  int r0 = blockIdx.x * 8;           // rows r = s*32+b, 8 consecutive share s
  int s = r0 >> 5, b0 = r0 & 31;
  for (int idx = threadIdx.x; idx < 8 * E_; idx += 256) {
    int i = idx / E_, k = idx - i * E_;
    int tok = sent[(b0 + i) * S_ + s];
    e[idx] = wordvec[(size_t)tok * E_ + k];
  }
  __syncthreads();
  int j0 = threadIdx.x * 4;
  float4 acc[8];
#pragma unroll
  for (int i = 0; i < 8; i++) acc[i] = make_float4(0.f, 0.f, 0.f, 0.f);
  for (int k = 0; k < E_; k++) {
    float4 w = *(const float4*)&Wxh[k * H_ + j0];
#pragma unroll
    for (int i = 0; i < 8; i++) {
      float ev = e[i * E_ + k];
      acc[i].x += ev * w.x; acc[i].y += ev * w.y;
      acc[i].z += ev * w.z; acc[i].w += ev * w.w;
    }
  }
  float4 bias = *(const float4*)&bh[j0];
#pragma unroll
  for (int i = 0; i < 8; i++) {
    float4 o = make_float4(acc[i].x + bias.x, acc[i].y + bias.y,
                           acc[i].z + bias.z, acc[i].w + bias.w);
    *(float4*)&pre[(size_t)(r0 + i) * H_ + j0] = o;
  }
}

// ---------------- K2: persistent recurrence, 64 blocks, barrier per step ----------------
// UNCHANGED from round 2 (verified: sc0/sc1 point-coherent exchange, ~4-5 us/step).
__global__ __launch_bounds__(256) void k_rnn(const float* __restrict__ Whh,
    const float* __restrict__ pre, __hip_bfloat16* __restrict__ hs,
    uint8_t* __restrict__ ws) {
  __shared__ __hip_bfloat16 ldsB[32 * 64 * 8];   // 32 KB, B-frag order
  __shared__ float ldsP[4 * 8 * 64];             // 8 KB cross-wave partials
  __shared__ __hip_bfloat16 ldsCt[32 * 24];      // C->A-frag transpose, padded
  const int jb = blockIdx.x;                     // 0..63
  const int tid = threadIdx.x;
  const int lane = tid & 63, w = tid >> 6;
  uint32_t* ctr = (uint32_t*)(ws + WS_CTR);
  uint8_t* hfrag = ws + WS_HFRAG;

  // stage Whh[:, jb*16 .. +16) as bf16 B-fragments
  for (int idx = tid; idx < 32 * 64; idx += 256) {
    int kc = idx >> 6, l = idx & 63;
    int n = l & 15;
    int k0 = kc * 32 + ((l >> 4) << 3);
    bf16x8 v;
#pragma unroll
    for (int i = 0; i < 8; i++)
      v[i] = (__bf16)Whh[(size_t)(k0 + i) * H_ + jb * 16 + n];
    *(bf16x8*)&ldsB[idx * 8] = v;
  }
  __syncthreads();

  for (int s = 0; s < SM1; s++) {
    const uint8_t* rbuf = hfrag + ((s & 1) ? 65536 : 0);
    uint8_t* wbuf = hfrag + ((s & 1) ? 0 : 65536);
    f32x4 acc0 = {0.f, 0.f, 0.f, 0.f}, acc1 = {0.f, 0.f, 0.f, 0.f};
    const int kc0 = w * 8;

    // batch-issue all 16 coherent A-frag loads, single drain, then MFMA
    bf16x8 a0[8], a1[8];
#pragma unroll
    for (int i = 0; i < 8; i++) {
      int kc = kc0 + i;
      frag_cvt c0, c1;
      c0.f = coh_load16(rbuf + (((kc * 2 + 0) * 64 + lane) << 4));
      c1.f = coh_load16(rbuf + (((kc * 2 + 1) * 64 + lane) << 4));
      a0[i] = c0.h; a1[i] = c1.h;
    }
    asm volatile("s_waitcnt vmcnt(0)" ::: "memory");
    __builtin_amdgcn_sched_barrier(0);   // rule #18: keep MFMAs below the drain
#pragma unroll
    for (int i = 0; i < 8; i++) {
      int kc = kc0 + i;
      bf16x8 b0 = *(const bf16x8*)&ldsB[(kc * 64 + lane) * 8];
      acc0 = __builtin_amdgcn_mfma_f32_16x16x32_bf16(a0[i], b0, acc0, 0, 0, 0);
      acc1 = __builtin_amdgcn_mfma_f32_16x16x32_bf16(a1[i], b0, acc1, 0, 0, 0);
    }
#pragma unroll
    for (int r = 0; r < 4; r++) {
      ldsP[(w * 8 + r) * 64 + lane] = acc0[r];
      ldsP[(w * 8 + 4 + r) * 64 + lane] = acc1[r];
    }
    __syncthreads();
    // epilogue split: wave w -> m-tile t=w>>1, regs (w&1)*2 + {0,1}
    {
      int t = w >> 1;
      int jl = lane & 15;
#pragma unroll
      for (int rr = 0; rr < 2; rr++) {
        int r = ((w & 1) << 1) + rr;
        float sum = 0.f;
#pragma unroll
        for (int p = 0; p < 4; p++) sum += ldsP[(p * 8 + t * 4 + r) * 64 + lane];
        int b = t * 16 + ((lane >> 4) << 2) + r;           // C/D row mapping (m89)
        float x = sum + pre[(size_t)(s * 32 + b) * H_ + jb * 16 + jl];
        float h = tanhf(x);
        __hip_bfloat16 hb = __float2bfloat16(h);
        hs[(size_t)(b * SM1 + s) * H_ + jb * 16 + jl] = hb;
        ldsCt[b * 24 + jl] = hb;
      }
    }
    __syncthreads();
    // wave 0: transpose to A-frag order, coherent-store next-step h buffer
    if (w == 0 && (lane >> 5) == (jb & 1)) {
      int kcw = jb >> 1;
#pragma unroll
      for (int t2 = 0; t2 < 2; t2++) {
        frag_cvt c;
        c.h = *(const bf16x8*)&ldsCt[(t2 * 16 + (lane & 15)) * 24 +
                                     (((lane >> 4) & 1) << 3)];
        coh_store16(wbuf + (((kcw * 2 + t2) * 64 + lane) << 4), c.f);
      }
    }
    // relaxed barrier: stores already point-coherent; no wbl2/inv needed.
    if (s < SM1 - 1) {
      if (tid == 0) {
        asm volatile("s_waitcnt vmcnt(0)" ::: "memory");
        __hip_atomic_fetch_add(&ctr[s], 1u, __ATOMIC_RELAXED, __HIP_MEMORY_SCOPE_AGENT);
        while (__hip_atomic_load(&ctr[s], __ATOMIC_RELAXED, __HIP_MEMORY_SCOPE_AGENT) < 64u)
          __builtin_amdgcn_s_sleep(2);
      }
      __syncthreads();
    }
  }
}

// ---------------- K3: logits = hs(4064x1024) @ Wout + bout, bf16 MFMA ----------------
// Round 3: (a) 2-phase double-buffered K-loop — STAGE(t+1) issued BEFORE the
// ds_read+MFMA of tile t, one vmcnt(0)+barrier per tile (m248v2 minimum-2-phase);
// (b) epilogue staged through padded LDS -> f32x4 stores, 256B contiguous per
// quad-row per instruction: only full 128B lines written (kills the 1.8x
// WRITE_SIZE amplification + RMW re-fetches seen in round-2 counters).
__global__ __launch_bounds__(256) void k_gemm(const __hip_bfloat16* __restrict__ A,
    const __hip_bfloat16* __restrict__ Bt, const float* __restrict__ bout,
    float* __restrict__ C) {
  // LDS: dbuf A/B tiles (2 x (16K A + 16K B) = 64 KB) overlapped with the
  // post-loop epilogue staging (4 waves x [64][68] f32 = 69632 B).
  __shared__ __align__(16) uint8_t lds[69632];
  int bid = blockIdx.x;
  int idx = bid & 255;
  int mt = idx & 31;
  int nt = ((bid >> 8) << 3) + (idx >> 5);   // N-panel swizzle: 32 mt share 8 nt panels
  int tid = threadIdx.x;
  int lane = tid & 63, w = tid >> 6;
  int wm = (w >> 1) << 6, wn = (w & 1) << 6;
  int mbase = mt * 128, nbase = nt * 128;
  int quad = lane >> 4, l15 = lane & 15;
  f32x4 acc[4][4];
#pragma unroll
  for (int t = 0; t < 4; t++)
#pragma unroll
    for (int u = 0; u < 4; u++) acc[t][u] = (f32x4){0.f, 0.f, 0.f, 0.f};

  auto STAGE = [&](int buf, int k0) {
    uint8_t* dA = lds + buf * 32768;
    uint8_t* dB = lds + buf * 32768 + 16384;
#pragma unroll
    for (int r = 0; r < 4; r++) {
      int L = r * 4096 + tid * 16;
      int row = L >> 7;
      int glog = ((L >> 4) & 7) ^ (row & 7);   // pre-swizzled global src, linear LDS dst
      int m = mbase + row; if (m > M_ - 1) m = M_ - 1;
      const uint8_t* g = (const uint8_t*)A + ((size_t)m * H_ + k0) * 2 + glog * 16;
      __builtin_amdgcn_global_load_lds((const __attribute__((address_space(1))) uint32_t*)g,
          (__attribute__((address_space(3))) uint32_t*)(dA + L), 16, 0, 0);
    }
#pragma unroll
    for (int r = 0; r < 4; r++) {
      int L = r * 4096 + tid * 16;
      int row = L >> 7;
      int glog = ((L >> 4) & 7) ^ (row & 7);
      int n = nbase + row;
      const uint8_t* g = (const uint8_t*)Bt + ((size_t)n * H_ + k0) * 2 + glog * 16;
      __builtin_amdgcn_global_load_lds((const __attribute__((address_space(1))) uint32_t*)g,
          (__attribute__((address_space(3))) uint32_t*)(dB + L), 16, 0, 0);
    }
  };

  // prologue: tile 0 into buf 0
  STAGE(0, 0);
  asm volatile("s_waitcnt vmcnt(0)" ::: "memory");
  __syncthreads();

  for (int t = 0; t < 16; t++) {
    int cur = t & 1;
    if (t < 15) STAGE(cur ^ 1, (t + 1) * 64);  // prefetch overlaps this tile's MFMAs
    const __hip_bfloat16* lA = (const __hip_bfloat16*)(lds + cur * 32768);
    const __hip_bfloat16* lB = (const __hip_bfloat16*)(lds + cur * 32768 + 16384);
#pragma unroll
    for (int kk = 0; kk < 64; kk += 32) {
      bf16x8 af[4], bfr[4];
#pragma unroll
      for (int tt = 0; tt < 4; tt++) {
        int row = wm + tt * 16 + l15;
        int gphys = ((kk >> 3) + quad) ^ (row & 7);
        af[tt] = *(const bf16x8*)&lA[row * 64 + gphys * 8];
      }
#pragma unroll
      for (int u = 0; u < 4; u++) {
        int row = wn + u * 16 + l15;
        int gphys = ((kk >> 3) + quad) ^ (row & 7);
        bfr[u] = *(const bf16x8*)&lB[row * 64 + gphys * 8];
      }
#pragma unroll
      for (int tt = 0; tt < 4; tt++)
#pragma unroll
        for (int u = 0; u < 4; u++)
          acc[tt][u] = __builtin_amdgcn_mfma_f32_16x16x32_bf16(af[tt], bfr[u], acc[tt][u], 0, 0, 0);
    }
    // single drain+barrier per tile: prefetch completed during MFMAs; also
    // orders buffer reuse (next iter overwrites buf[cur^1]) and, on the last
    // iter, protects the epilogue's aliasing of the LDS region.
    asm volatile("s_waitcnt vmcnt(0)" ::: "memory");
    __syncthreads();
  }

  // epilogue: stage per-wave 64x64 C-tile (bias added) into private [64][68]
  // f32 LDS region (2-way banks max = free), then f32x4 stores: 16 lanes cover
  // 256 contiguous bytes per quad-row -> full-line writes only.
  float* ep = (float*)(lds + w * 17408);
#pragma unroll
  for (int u = 0; u < 4; u++) {
    float bias = bout[nbase + wn + u * 16 + l15];
#pragma unroll
    for (int tt = 0; tt < 4; tt++) {
#pragma unroll
      for (int r = 0; r < 4; r++) {
        int lr = tt * 16 + quad * 4 + r;       // C/D row mapping (m89)
        ep[lr * 68 + u * 16 + l15] = acc[tt][u][r] + bias;
      }
    }
  }
  // same-wave LDS ops complete in order; region is wave-private -> no barrier
#pragma unroll
  for (int i = 0; i < 16; i++) {
    int lr = i * 4 + quad;
    int gr = mbase + wm + lr;
    if (gr < M_) {
      f32x4 v = *(const f32x4*)&ep[lr * 68 + l15 * 4];
      *(f32x4*)&C[(size_t)gr * V_ + nbase + wn + l15 * 4] = v;
    }
  }
}

// ---------------- K4: masked NLL via online logsumexp ----------------
__global__ __launch_bounds__(256) void k_loss(const float* __restrict__ logits,
    const int* __restrict__ sent, const int* __restrict__ length,
    float* __restrict__ nll_acc) {
  int r = blockIdx.x;
  int b = r / SM1, s = r - b * SM1;
  if (s >= length[b]) return;
  const float* row = logits + (size_t)r * V_;
  float m = -3.0e38f, l = 0.f;
  for (int v = threadIdx.x; v < V_; v += 256) {
    float x = row[v];
    float nm = fmaxf(m, x);
    l = l * __expf(m - nm) + __expf(x - nm);
    m = nm;
  }
#pragma unroll
  for (int off = 1; off < 64; off <<= 1) {
    float m2 = __shfl_xor(m, off);
    float l2 = __shfl_xor(l, off);
    float nm = fmaxf(m, m2);
    l = l * __expf(m - nm) + l2 * __expf(m2 - nm);
    m = nm;
  }
  __shared__ float sm[4], sl[4];
  int wv = threadIdx.x >> 6;
  if ((threadIdx.x & 63) == 0) { sm[wv] = m; sl[wv] = l; }
  __syncthreads();
  if (threadIdx.x == 0) {
    m = sm[0]; l = sl[0];
    for (int p = 1; p < 4; p++) {
      float nm = fmaxf(m, sm[p]);
      l = l * __expf(m - nm) + sl[p] * __expf(sm[p] - nm);
      m = nm;
    }
    int tgt = sent[b * S_ + s + 1];
    float nll = m + logf(l) - row[tgt];
    atomicAdd(nll_acc, nll);
  }
}

// ---------------- K5: loss = nll_sum / sum(length) ----------------
__global__ void k_final(const float* __restrict__ nll_acc,
                        const int* __restrict__ length, float* __restrict__ out) {
  float cnt = 0.f;
  for (int b = 0; b < B_; b++) cnt += (float)length[b];
  out[0] = nll_acc[0] / cnt;
}

extern "C" void kernel_launch(void* const* d_in, const int* in_sizes, int n_in,
                              void* d_out, int out_size, void* d_ws, size_t ws_size,
                              hipStream_t stream) {
  const int* sent      = (const int*)d_in[0];
  const int* length    = (const int*)d_in[1];
  const float* wordvec = (const float*)d_in[2];
  const float* Wxh     = (const float*)d_in[3];
  const float* Whh     = (const float*)d_in[4];
  const float* bh      = (const float*)d_in[5];
  const float* Wout    = (const float*)d_in[6];
  const float* bout    = (const float*)d_in[7];
  float* out = (float*)d_out;
  uint8_t* ws = (uint8_t*)d_ws;

  // zero barrier counters + nll accumulator + h0 frag buffers
  hipMemsetAsync(ws, 0, 135168, stream);

  __hip_bfloat16* wbt = (__hip_bfloat16*)(ws + WS_WBT);
  float* pre          = (float*)(ws + WS_PRE);
  __hip_bfloat16* hs  = (__hip_bfloat16*)(ws + WS_HS);
  float* logits       = out + 1;

  k_wout_cvt<<<32000, 256, 0, stream>>>(Wout, wbt);
  k_pre<<<508, 256, 0, stream>>>(sent, wordvec, Wxh, bh, pre);
  k_rnn<<<64, 256, 0, stream>>>(Whh, pre, hs, ws);
  k_gemm<<<8000, 256, 0, stream>>>(hs, wbt, bout, logits);
  k_loss<<<4064, 256, 0, stream>>>(logits, sent, length, (float*)(ws + WS_NLL));
  k_final<<<1, 1, 0, stream>>>((const float*)(ws + WS_NLL), length, out);
}